// Round 5
// baseline (576.358 us; speedup 1.0000x reference)
//
#include <hip/hip_runtime.h>

// GAT fused kernel for MI355X (gfx950) -- round 5.
// B=32768 graphs, N=14 nodes, F=C=128, E=64 edges (+14 self loops).
// Inputs f32 (edge_list int32); output f32: pred[32768] ++ attn[32768*196].
//
// R2->R4 evidence: throughput scales ~linearly with waves/CU (8->556us,
// 16->211..222us); waves are ~90% stalled on dependent chains; VALU floor at
// full occupancy ~60us. This round:
//  1. 24 waves/CU: no block-shared W (L2-direct B-frags, proven equal in R4),
//     WaveLds 5632B x 8 waves = 45KB/block -> 3 blocks/CU, launch_bounds(512,6).
//  2. Scores via MFMA: setup packs a 9th B-tile (cols: W@a_s, W@a_d, 0...) per
//     k-step; as_n/ad_n come out of hacc[8] -- kills both 32-shfl butterflies,
//     64 FMAs and asv/adv loads per layer.
//  3. Pb phase deleted: P@h A-frag reads Pf (f32) * mz directly (one less
//     fence + 512B LDS).

#define NEG_SLOPE 0.2f

typedef __bf16 bf16x8 __attribute__((ext_vector_type(8)));
typedef float f32x4 __attribute__((ext_vector_type(4)));
typedef unsigned short us4v __attribute__((ext_vector_type(4)));
typedef unsigned short us8v __attribute__((ext_vector_type(8)));

static __device__ __forceinline__ unsigned short f2bf(float f) {
  unsigned u = __builtin_bit_cast(unsigned, f);
  return (unsigned short)((u + 0x7FFFu + ((u >> 16) & 1u)) >> 16); // RNE, finite
}

// ---------------- setup: extended W frags (9 tiles) + weffc ----------------
// Frag slot s = ((lr*4+ks)*9+t)*64+lane, 8 shorts each.
// t<8 : B[k=ks*32+q*8+j][n=t*16+l] = W[k][n]
// t==8: l==0 -> (W@a_s)[k], l==1 -> (W@a_d)[k], else 0   (scores tile)
__global__ void gat_setup_kernel(const float* __restrict__ W1, const float* __restrict__ W2,
                                 const float* __restrict__ as1, const float* __restrict__ ad1,
                                 const float* __restrict__ as2, const float* __restrict__ ad2,
                                 const float* __restrict__ Wl, const float* __restrict__ bl,
                                 const float* __restrict__ Wp, const float* __restrict__ bp,
                                 unsigned short* __restrict__ wfrag, float* __restrict__ weffc) {
  const int blk = blockIdx.x, tid = threadIdx.x; // 19 blocks x 256
  if (blk < 18) {
    int slot = blk * 256 + tid;
    int lane = slot & 63, frag = slot >> 6;        // frag = lr*36 + ks*9 + t
    int lr = frag / 36, rem = frag % 36, ks = rem / 9, t = rem % 9;
    const float* W = lr ? W2 : W1;
    int q = lane >> 4, l = lane & 15;
    int k0 = ks * 32 + q * 8;
    us8v hv;
    if (t < 8) {
      int n = t * 16 + l;
      #pragma unroll
      for (int j = 0; j < 8; ++j) hv[j] = f2bf(W[(k0 + j) * 128 + n]);
    } else {
      const float* vec = l ? (lr ? ad2 : ad1) : (lr ? as2 : as1);
      #pragma unroll
      for (int j = 0; j < 8; ++j) {
        float s = 0.f;
        if (l < 2) {
          const float* wr = W + (size_t)(k0 + j) * 128;
          for (int c = 0; c < 128; ++c) s += wr[c] * vec[c];
        }
        hv[j] = f2bf(s);
      }
    }
    *(us8v*)(wfrag + slot * 8) = hv;
  } else {
    // weffc[(t*64+lane)*4+r] = (4q+r)<14 ? sum_c Wl[((4q+r)*128+t*16+l)*64+c]*Wp[c] : 0
    for (int i = tid; i < 2048; i += 256) {
      int r = i & 3, lane = (i >> 2) & 63, t = i >> 8;
      int q = lane >> 4, l = lane & 15;
      int row = 4 * q + r, col = t * 16 + l;
      float s = 0.f;
      if (row < 14) {
        const float* wl = Wl + (size_t)(row * 128 + col) * 64;
        #pragma unroll 8
        for (int c = 0; c < 64; ++c) s += wl[c] * Wp[c];
      }
      weffc[i] = s;
    }
    if (tid == 0) {
      float s = 0.f;
      for (int c = 0; c < 64; ++c) s += bl[c] * Wp[c];
      weffc[2048] = s + bp[0];
    }
  }
}

// Wave-private LDS scratch, 5632 B. 8 waves -> 45,056 B/block -> 3 blocks/CU.
struct __align__(16) WaveLds {
  unsigned short xh[2176]; // xg[16][136] (layer-2 A-op) UNION ht[128][16] (P@h B-op)
  float Pf[256];           // unnormalized P f32 [16][16] [dst][src] (atomicAdd)
  float asn[16], adn[16], mz[16];
  int emask[16];           // per-src bitmask of existing dsts
};

__global__ __launch_bounds__(512, 6) void gat_kernel(
    const float* __restrict__ feat, const int* __restrict__ edges,
    const float* __restrict__ b1v, const float* __restrict__ b2v,
    const unsigned short* __restrict__ wfrag, const float* __restrict__ weffc,
    float* __restrict__ out) {
  __shared__ WaveLds wls[8];
  const int tid = threadIdx.x;
  const int wave = tid >> 6, lane = tid & 63;
  const int q = lane >> 4, l = lane & 15;
  const int g = blockIdx.x * 8 + wave;
  WaveLds& S = wls[wave];

  us8v z8v = {0, 0, 0, 0, 0, 0, 0, 0};
  const bf16x8 zf = __builtin_bit_cast(bf16x8, z8v);

  // ---- feature -> layer-1 A-fragments (regs); rows m=l>=14 zero ----
  bf16x8 af1[4];
  if (l < 14) {
    const float* fb = feat + (size_t)g * 1792 + l * 128 + q * 8;
    #pragma unroll
    for (int ks = 0; ks < 4; ++ks) {
      f32x4 v0 = *(const f32x4*)(fb + ks * 32);
      f32x4 v1 = *(const f32x4*)(fb + ks * 32 + 4);
      us8v hv;
      hv[0] = f2bf(v0[0]); hv[1] = f2bf(v0[1]); hv[2] = f2bf(v0[2]); hv[3] = f2bf(v0[3]);
      hv[4] = f2bf(v1[0]); hv[5] = f2bf(v1[1]); hv[6] = f2bf(v1[2]); hv[7] = f2bf(v1[3]);
      af1[ks] = __builtin_bit_cast(bf16x8, hv);
    }
  } else {
    #pragma unroll
    for (int ks = 0; ks < 4; ++ks) af1[ks] = zf;
  }
  // edge endpoints, one edge per lane (E=64)
  int esrc, edst;
  { const int2 e2 = *(const int2*)(edges + (size_t)g * 128 + lane * 2); esrc = e2.x; edst = e2.y; }
  if (lane < 16) S.emask[lane] = 0; // ordered before atomicOr by the phase-1 fence

  f32x4 oacc[8];

  for (int lr = 0; lr < 2; ++lr) {
    const float* bsv = lr ? b2v : b1v;

    // ---- h = x@W + scores tile (M=16, 9 N-tiles, 4 K-steps); B-frags from L2 ----
    f32x4 hacc[9];
    #pragma unroll
    for (int t = 0; t < 9; ++t) hacc[t] = (f32x4){0.f, 0.f, 0.f, 0.f};
    #pragma unroll
    for (int ks = 0; ks < 4; ++ks) {
      bf16x8 af = lr ? *(const bf16x8*)(&S.xh[l * 136 + ks * 32 + q * 8]) : af1[ks];
      const unsigned short* wk = wfrag + ((lr * 4 + ks) * 9) * 512 + lane * 8;
      #pragma unroll
      for (int t = 0; t < 8; ++t) {
        bf16x8 bfv = *(const bf16x8*)(wk + t * 512); // 16B/lane, L2-hot
        hacc[t] = __builtin_amdgcn_mfma_f32_16x16x32_bf16(af, bfv, hacc[t], 0, 0, 0);
      }
      bf16x8 bsc = (l < 2) ? *(const bf16x8*)(wk + 8 * 512) : zf; // scores tile (cols 0,1)
      hacc[8] = __builtin_amdgcn_mfma_f32_16x16x32_bf16(af, bsc, hacc[8], 0, 0, 0);
    }

    // ---- scores straight out of hacc[8]: D[row=4q+r][col=l], l=0->as, l=1->ad ----
    if (l < 2) {
      float* dst = l ? S.adn : S.asn;
      *(f32x4*)(dst + 4 * q) = hacc[8];
    }

    // ---- h -> ht[128][16] bf16 (B-op of P@h): ht[col][node] ----
    #pragma unroll
    for (int t = 0; t < 8; ++t) {
      us4v hv;
      hv[0] = f2bf(hacc[t][0]); hv[1] = f2bf(hacc[t][1]);
      hv[2] = f2bf(hacc[t][2]); hv[3] = f2bf(hacc[t][3]);
      *(us4v*)(&S.xh[(t * 16 + l) * 16 + q * 4]) = hv;
    }
    *(f32x4*)(&S.Pf[lane * 4]) = (f32x4){0.f, 0.f, 0.f, 0.f}; // all 256 zeroed
    __threadfence_block();

    // ---- edges: ev = exp(leaky(asn[src]+adn[dst])); accumulate unnormalized P ----
    float f0 = S.asn[esrc] + S.adn[edst];
    float ev = __expf(f0 > 0.f ? f0 : NEG_SLOPE * f0);
    atomicAdd(&S.Pf[edst * 16 + esrc], ev);
    if (lr == 0) atomicOr(&S.emask[esrc], 1 << edst);
    if (lane < 14) { // self loops
      float f2 = S.asn[lane] + S.adn[lane];
      atomicAdd(&S.Pf[lane * 17], __expf(f2 > 0.f ? f2 : NEG_SLOPE * f2));
      if (lr == 0) atomicOr(&S.emask[lane], 1 << lane);
    }
    __threadfence_block();

    // ---- per-dst 1/z; mz[14..15]=0 kills pad rows in P@h ----
    if (lane < 16) {
      f32x4 s0 = *(const f32x4*)(&S.Pf[lane * 16]) + *(const f32x4*)(&S.Pf[lane * 16 + 4]) +
                 *(const f32x4*)(&S.Pf[lane * 16 + 8]) + *(const f32x4*)(&S.Pf[lane * 16 + 12]);
      float z = s0[0] + s0[1] + s0[2] + s0[3];
      S.mz[lane] = (lane < 14) ? 1.f / z : 0.f;
    }
    __threadfence_block();

    // ---- out = P @ h + b; A-frag = bf16(Pf[l][8q+j] * mz[l]), no Pb staging ----
    #pragma unroll
    for (int t = 0; t < 8; ++t) {
      float bb = bsv[t * 16 + l];
      oacc[t] = (f32x4){bb, bb, bb, bb};
    }
    bf16x8 paf = zf;
    if (q < 2) {
      f32x4 p0 = *(const f32x4*)(&S.Pf[l * 16 + q * 8]);
      f32x4 p1 = *(const f32x4*)(&S.Pf[l * 16 + q * 8 + 4]);
      float m = S.mz[l];
      us8v pv;
      pv[0] = f2bf(p0[0] * m); pv[1] = f2bf(p0[1] * m);
      pv[2] = f2bf(p0[2] * m); pv[3] = f2bf(p0[3] * m);
      pv[4] = f2bf(p1[0] * m); pv[5] = f2bf(p1[1] * m);
      pv[6] = f2bf(p1[2] * m); pv[7] = f2bf(p1[3] * m);
      paf = __builtin_bit_cast(bf16x8, pv);
    }
    #pragma unroll
    for (int t = 0; t < 8; ++t) {
      bf16x8 hbf = (q < 2) ? *(const bf16x8*)(&S.xh[(t * 16 + l) * 16 + q * 8]) : zf;
      oacc[t] = __builtin_amdgcn_mfma_f32_16x16x32_bf16(paf, hbf, oacc[t], 0, 0, 0);
    }

    if (lr == 0) {
      // x2 = relu(out1) -> xg[16][136] for layer-2 A-op (rows 14/15 = relu(b1) wiped
      // downstream by mz/weffc masks; written anyway for defined bits)
      __threadfence_block();
      #pragma unroll
      for (int t = 0; t < 8; ++t) {
        #pragma unroll
        for (int r = 0; r < 4; ++r) {
          float v = fmaxf(oacc[t][r], 0.f);
          S.xh[(4 * q + r) * 136 + t * 16 + l] = f2bf(v);
        }
      }
      __threadfence_block();
    }
  }

  // ---- pred = sigmoid(sum oacc .* weffc + beff); weffc pre-masked rows>=14 ----
  float part = 0.f;
  #pragma unroll
  for (int t = 0; t < 8; ++t) {
    f32x4 wv = *(const f32x4*)(weffc + t * 256 + lane * 4); // L1/L2-hot
    part += oacc[t][0] * wv[0] + oacc[t][1] * wv[1] + oacc[t][2] * wv[2] + oacc[t][3] * wv[3];
  }
  #pragma unroll
  for (int m = 1; m < 64; m <<= 1) part += __shfl_xor(part, m, 64);
  if (lane == 0) out[g] = 1.f / (1.f + __expf(-(part + weffc[2048])));

  // ---- attn flush: alpha recomputed from layer-2 asn/adn/mz + emask ----
  {
    float* oa = out + 32768 + (size_t)g * 196;
    #pragma unroll
    for (int k = 0; k < 4; ++k) {
      int i = lane + k * 64;
      if (i < 196) {
        int s = (i * 4682) >> 16; // floor(i/14) for i in [0,196)
        int d = i - s * 14;
        float a = 0.f;
        if ((S.emask[s] >> d) & 1) {
          float f = S.asn[s] + S.adn[d];
          a = __expf(f > 0.f ? f : NEG_SLOPE * f) * S.mz[d];
        }
        oa[i] = a;
      }
    }
  }
}

extern "C" void kernel_launch(void* const* d_in, const int* in_sizes, int n_in,
                              void* d_out, int out_size, void* d_ws, size_t ws_size,
                              hipStream_t stream) {
  const float* feat = (const float*)d_in[0];
  const int* edges = (const int*)d_in[1];
  const float* W1 = (const float*)d_in[2];
  const float* as1 = (const float*)d_in[3];
  const float* ad1 = (const float*)d_in[4];
  const float* b1 = (const float*)d_in[5];
  const float* W2 = (const float*)d_in[6];
  const float* as2 = (const float*)d_in[7];
  const float* ad2 = (const float*)d_in[8];
  const float* b2 = (const float*)d_in[9];
  const float* Wl = (const float*)d_in[10];
  const float* bl = (const float*)d_in[11];
  const float* Wp = (const float*)d_in[12];
  const float* bp = (const float*)d_in[13];

  unsigned short* wfrag = (unsigned short*)d_ws;          // 73,728 B (72 frags)
  float* weffc = (float*)((char*)d_ws + 73728);           // 2049 f32

  gat_setup_kernel<<<19, 256, 0, stream>>>(W1, W2, as1, ad1, as2, ad2,
                                           Wl, bl, Wp, bp, wfrag, weffc);
  gat_kernel<<<4096, 512, 0, stream>>>(feat, edges, b1, b2, wfrag, weffc,
                                       (float*)d_out);
}

// Round 6
// 488.118 us; speedup vs baseline: 1.1808x; 1.1808x over previous
//
#include <hip/hip_runtime.h>

// GAT fused kernel for MI355X (gfx950) -- round 6.
// B=32768 graphs, N=14 nodes, F=C=128, E=64 edges (+14 self loops).
// Inputs f32 (edge_list int32); output f32: pred[32768] ++ attn[32768*196].
//
// R5 post-mortem: __launch_bounds__(512,6) forced VGPR 64->40 => ~460MB scratch
// spill traffic (WRITE 41->330MB) and 304us. R6 keeps R5's structure (MFMA-fused
// scores, no Pb staging) and gets occupancy from LDS geometry instead:
//   256-thr blocks, 4 waves x 5632B = 22,528B/block -> 7 blocks/CU = 28 waves/CU,
//   launch_bounds(256,4) leaves VGPR cap at 128 (R3 measured 64 under this bound,
//   no spill). VGPR floor of this kernel is ~64 -- never bound below 80.

#define NEG_SLOPE 0.2f

typedef __bf16 bf16x8 __attribute__((ext_vector_type(8)));
typedef float f32x4 __attribute__((ext_vector_type(4)));
typedef unsigned short us4v __attribute__((ext_vector_type(4)));
typedef unsigned short us8v __attribute__((ext_vector_type(8)));

static __device__ __forceinline__ unsigned short f2bf(float f) {
  unsigned u = __builtin_bit_cast(unsigned, f);
  return (unsigned short)((u + 0x7FFFu + ((u >> 16) & 1u)) >> 16); // RNE, finite
}

// ---------------- setup: extended W frags (9 tiles) + weffc ----------------
// Frag slot s = ((lr*4+ks)*9+t)*64+lane, 8 shorts each.
// t<8 : B[k=ks*32+q*8+j][n=t*16+l] = W[k][n]
// t==8: l==0 -> (W@a_s)[k], l==1 -> (W@a_d)[k], else 0   (scores tile)
__global__ void gat_setup_kernel(const float* __restrict__ W1, const float* __restrict__ W2,
                                 const float* __restrict__ as1, const float* __restrict__ ad1,
                                 const float* __restrict__ as2, const float* __restrict__ ad2,
                                 const float* __restrict__ Wl, const float* __restrict__ bl,
                                 const float* __restrict__ Wp, const float* __restrict__ bp,
                                 unsigned short* __restrict__ wfrag, float* __restrict__ weffc) {
  const int blk = blockIdx.x, tid = threadIdx.x; // 19 blocks x 256
  if (blk < 18) {
    int slot = blk * 256 + tid;
    int lane = slot & 63, frag = slot >> 6;        // frag = lr*36 + ks*9 + t
    int lr = frag / 36, rem = frag % 36, ks = rem / 9, t = rem % 9;
    const float* W = lr ? W2 : W1;
    int q = lane >> 4, l = lane & 15;
    int k0 = ks * 32 + q * 8;
    us8v hv;
    if (t < 8) {
      int n = t * 16 + l;
      #pragma unroll
      for (int j = 0; j < 8; ++j) hv[j] = f2bf(W[(k0 + j) * 128 + n]);
    } else {
      const float* vec = l ? (lr ? ad2 : ad1) : (lr ? as2 : as1);
      #pragma unroll
      for (int j = 0; j < 8; ++j) {
        float s = 0.f;
        if (l < 2) {
          const float* wr = W + (size_t)(k0 + j) * 128;
          for (int c = 0; c < 128; ++c) s += wr[c] * vec[c];
        }
        hv[j] = f2bf(s);
      }
    }
    *(us8v*)(wfrag + slot * 8) = hv;
  } else {
    // weffc[(t*64+lane)*4+r] = (4q+r)<14 ? sum_c Wl[((4q+r)*128+t*16+l)*64+c]*Wp[c] : 0
    for (int i = tid; i < 2048; i += 256) {
      int r = i & 3, lane = (i >> 2) & 63, t = i >> 8;
      int q = lane >> 4, l = lane & 15;
      int row = 4 * q + r, col = t * 16 + l;
      float s = 0.f;
      if (row < 14) {
        const float* wl = Wl + (size_t)(row * 128 + col) * 64;
        #pragma unroll 8
        for (int c = 0; c < 64; ++c) s += wl[c] * Wp[c];
      }
      weffc[i] = s;
    }
    if (tid == 0) {
      float s = 0.f;
      for (int c = 0; c < 64; ++c) s += bl[c] * Wp[c];
      weffc[2048] = s + bp[0];
    }
  }
}

// Wave-private LDS scratch, 5632 B. 4 waves -> 22,528 B/block -> 7 blocks/CU.
struct __align__(16) WaveLds {
  unsigned short xh[2176]; // xg[16][136] (layer-2 A-op) UNION ht[128][16] (P@h B-op)
  float Pf[256];           // unnormalized P f32 [16][16] [dst][src] (atomicAdd)
  float asn[16], adn[16], mz[16];
  int emask[16];           // per-src bitmask of existing dsts
};

__global__ __launch_bounds__(256, 4) void gat_kernel(
    const float* __restrict__ feat, const int* __restrict__ edges,
    const float* __restrict__ b1v, const float* __restrict__ b2v,
    const unsigned short* __restrict__ wfrag, const float* __restrict__ weffc,
    float* __restrict__ out) {
  __shared__ WaveLds wls[4];
  const int tid = threadIdx.x;
  const int wave = tid >> 6, lane = tid & 63;
  const int q = lane >> 4, l = lane & 15;
  const int g = blockIdx.x * 4 + wave;
  WaveLds& S = wls[wave];

  us8v z8v = {0, 0, 0, 0, 0, 0, 0, 0};
  const bf16x8 zf = __builtin_bit_cast(bf16x8, z8v);

  // ---- feature -> layer-1 A-fragments (regs); rows m=l>=14 zero ----
  bf16x8 af1[4];
  if (l < 14) {
    const float* fb = feat + (size_t)g * 1792 + l * 128 + q * 8;
    #pragma unroll
    for (int ks = 0; ks < 4; ++ks) {
      f32x4 v0 = *(const f32x4*)(fb + ks * 32);
      f32x4 v1 = *(const f32x4*)(fb + ks * 32 + 4);
      us8v hv;
      hv[0] = f2bf(v0[0]); hv[1] = f2bf(v0[1]); hv[2] = f2bf(v0[2]); hv[3] = f2bf(v0[3]);
      hv[4] = f2bf(v1[0]); hv[5] = f2bf(v1[1]); hv[6] = f2bf(v1[2]); hv[7] = f2bf(v1[3]);
      af1[ks] = __builtin_bit_cast(bf16x8, hv);
    }
  } else {
    #pragma unroll
    for (int ks = 0; ks < 4; ++ks) af1[ks] = zf;
  }
  // edge endpoints, one edge per lane (E=64)
  int esrc, edst;
  { const int2 e2 = *(const int2*)(edges + (size_t)g * 128 + lane * 2); esrc = e2.x; edst = e2.y; }
  if (lane < 16) S.emask[lane] = 0; // ordered before atomicOr by the phase-1 fence

  f32x4 oacc[8];

  for (int lr = 0; lr < 2; ++lr) {
    const float* bsv = lr ? b2v : b1v;

    // ---- h = x@W + scores tile (M=16, 9 N-tiles, 4 K-steps); B-frags from L2 ----
    f32x4 hacc[9];
    #pragma unroll
    for (int t = 0; t < 9; ++t) hacc[t] = (f32x4){0.f, 0.f, 0.f, 0.f};
    #pragma unroll
    for (int ks = 0; ks < 4; ++ks) {
      bf16x8 af = lr ? *(const bf16x8*)(&S.xh[l * 136 + ks * 32 + q * 8]) : af1[ks];
      const unsigned short* wk = wfrag + ((lr * 4 + ks) * 9) * 512 + lane * 8;
      #pragma unroll
      for (int t = 0; t < 8; ++t) {
        bf16x8 bfv = *(const bf16x8*)(wk + t * 512); // 16B/lane, L2-hot
        hacc[t] = __builtin_amdgcn_mfma_f32_16x16x32_bf16(af, bfv, hacc[t], 0, 0, 0);
      }
      bf16x8 bsc = (l < 2) ? *(const bf16x8*)(wk + 8 * 512) : zf; // scores tile (cols 0,1)
      hacc[8] = __builtin_amdgcn_mfma_f32_16x16x32_bf16(af, bsc, hacc[8], 0, 0, 0);
    }

    // ---- scores straight out of hacc[8]: D[row=4q+r][col=l], l=0->as, l=1->ad ----
    if (l < 2) {
      float* dst = l ? S.adn : S.asn;
      *(f32x4*)(dst + 4 * q) = hacc[8];
    }

    // ---- h -> ht[128][16] bf16 (B-op of P@h): ht[col][node] ----
    #pragma unroll
    for (int t = 0; t < 8; ++t) {
      us4v hv;
      hv[0] = f2bf(hacc[t][0]); hv[1] = f2bf(hacc[t][1]);
      hv[2] = f2bf(hacc[t][2]); hv[3] = f2bf(hacc[t][3]);
      *(us4v*)(&S.xh[(t * 16 + l) * 16 + q * 4]) = hv;
    }
    *(f32x4*)(&S.Pf[lane * 4]) = (f32x4){0.f, 0.f, 0.f, 0.f}; // all 256 zeroed
    __threadfence_block();

    // ---- edges: ev = exp(leaky(asn[src]+adn[dst])); accumulate unnormalized P ----
    float f0 = S.asn[esrc] + S.adn[edst];
    float ev = __expf(f0 > 0.f ? f0 : NEG_SLOPE * f0);
    atomicAdd(&S.Pf[edst * 16 + esrc], ev);
    if (lr == 0) atomicOr(&S.emask[esrc], 1 << edst);
    if (lane < 14) { // self loops
      float f2 = S.asn[lane] + S.adn[lane];
      atomicAdd(&S.Pf[lane * 17], __expf(f2 > 0.f ? f2 : NEG_SLOPE * f2));
      if (lr == 0) atomicOr(&S.emask[lane], 1 << lane);
    }
    __threadfence_block();

    // ---- per-dst 1/z; mz[14..15]=0 kills pad rows in P@h ----
    if (lane < 16) {
      f32x4 s0 = *(const f32x4*)(&S.Pf[lane * 16]) + *(const f32x4*)(&S.Pf[lane * 16 + 4]) +
                 *(const f32x4*)(&S.Pf[lane * 16 + 8]) + *(const f32x4*)(&S.Pf[lane * 16 + 12]);
      float z = s0[0] + s0[1] + s0[2] + s0[3];
      S.mz[lane] = (lane < 14) ? 1.f / z : 0.f;
    }
    __threadfence_block();

    // ---- out = P @ h + b; A-frag = bf16(Pf[l][8q+j] * mz[l]), no Pb staging ----
    #pragma unroll
    for (int t = 0; t < 8; ++t) {
      float bb = bsv[t * 16 + l];
      oacc[t] = (f32x4){bb, bb, bb, bb};
    }
    bf16x8 paf = zf;
    if (q < 2) {
      f32x4 p0 = *(const f32x4*)(&S.Pf[l * 16 + q * 8]);
      f32x4 p1 = *(const f32x4*)(&S.Pf[l * 16 + q * 8 + 4]);
      float m = S.mz[l];
      us8v pv;
      pv[0] = f2bf(p0[0] * m); pv[1] = f2bf(p0[1] * m);
      pv[2] = f2bf(p0[2] * m); pv[3] = f2bf(p0[3] * m);
      pv[4] = f2bf(p1[0] * m); pv[5] = f2bf(p1[1] * m);
      pv[6] = f2bf(p1[2] * m); pv[7] = f2bf(p1[3] * m);
      paf = __builtin_bit_cast(bf16x8, pv);
    }
    #pragma unroll
    for (int t = 0; t < 8; ++t) {
      bf16x8 hbf = (q < 2) ? *(const bf16x8*)(&S.xh[(t * 16 + l) * 16 + q * 8]) : zf;
      oacc[t] = __builtin_amdgcn_mfma_f32_16x16x32_bf16(paf, hbf, oacc[t], 0, 0, 0);
    }

    if (lr == 0) {
      // x2 = relu(out1) -> xg[16][136] for layer-2 A-op
      __threadfence_block();
      #pragma unroll
      for (int t = 0; t < 8; ++t) {
        #pragma unroll
        for (int r = 0; r < 4; ++r) {
          float v = fmaxf(oacc[t][r], 0.f);
          S.xh[(4 * q + r) * 136 + t * 16 + l] = f2bf(v);
        }
      }
      __threadfence_block();
    }
  }

  // ---- pred = sigmoid(sum oacc .* weffc + beff); weffc pre-masked rows>=14 ----
  float part = 0.f;
  #pragma unroll
  for (int t = 0; t < 8; ++t) {
    f32x4 wv = *(const f32x4*)(weffc + t * 256 + lane * 4); // L1/L2-hot
    part += oacc[t][0] * wv[0] + oacc[t][1] * wv[1] + oacc[t][2] * wv[2] + oacc[t][3] * wv[3];
  }
  #pragma unroll
  for (int m = 1; m < 64; m <<= 1) part += __shfl_xor(part, m, 64);
  if (lane == 0) out[g] = 1.f / (1.f + __expf(-(part + weffc[2048])));

  // ---- attn flush: alpha recomputed from layer-2 asn/adn/mz + emask ----
  {
    float* oa = out + 32768 + (size_t)g * 196;
    #pragma unroll
    for (int k = 0; k < 4; ++k) {
      int i = lane + k * 64;
      if (i < 196) {
        int s = (i * 4682) >> 16; // floor(i/14) for i in [0,196)
        int d = i - s * 14;
        float a = 0.f;
        if ((S.emask[s] >> d) & 1) {
          float f = S.asn[s] + S.adn[d];
          a = __expf(f > 0.f ? f : NEG_SLOPE * f) * S.mz[d];
        }
        oa[i] = a;
      }
    }
  }
}

extern "C" void kernel_launch(void* const* d_in, const int* in_sizes, int n_in,
                              void* d_out, int out_size, void* d_ws, size_t ws_size,
                              hipStream_t stream) {
  const float* feat = (const float*)d_in[0];
  const int* edges = (const int*)d_in[1];
  const float* W1 = (const float*)d_in[2];
  const float* as1 = (const float*)d_in[3];
  const float* ad1 = (const float*)d_in[4];
  const float* b1 = (const float*)d_in[5];
  const float* W2 = (const float*)d_in[6];
  const float* as2 = (const float*)d_in[7];
  const float* ad2 = (const float*)d_in[8];
  const float* b2 = (const float*)d_in[9];
  const float* Wl = (const float*)d_in[10];
  const float* bl = (const float*)d_in[11];
  const float* Wp = (const float*)d_in[12];
  const float* bp = (const float*)d_in[13];

  unsigned short* wfrag = (unsigned short*)d_ws;          // 73,728 B (72 frags)
  float* weffc = (float*)((char*)d_ws + 73728);           // 2049 f32

  gat_setup_kernel<<<19, 256, 0, stream>>>(W1, W2, as1, ad1, as2, ad2,
                                           Wl, bl, Wp, bp, wfrag, weffc);
  gat_kernel<<<8192, 256, 0, stream>>>(feat, edges, b1, b2, wfrag, weffc,
                                       (float*)d_out);
}